// Round 13
// baseline (56955.823 us; speedup 1.0000x reference)
//
#include <hip/hip_runtime.h>

// LSTM: S=4096, I=64, H=1024, O=1, fp32.
// Persistent cooperative kernel, 128 blocks x 512 threads (r9 champion base).
// R13: cache-served polling. r9-r12 FETCH_SIZE (~47MB/step HBM reads vs a
// 16KB slot array) proves agent-scope atomic loads are served from HBM
// (sc0+sc1 path misses/bypasses MALL) -> every poll iteration ~900cy+queue.
// Fix: poll with workgroup-scope atomic loads (plain cacheable
// global_load_dwordx2) preceded by `buffer_inv sc1` each iteration (the
// same L1+L2 flash-invalidate the compiler emits for agent acquires), so
// loads miss L2 and hit MALL (~400cy) where the producers' sc1 stores land.
// Correctness: tag+value share one 8B word (one line-read, no tearing);
// staleness only delays. Collateral inv is cheap: weights in registers,
// h in LDS; only x-lines refetch. Publish stays agent-scope atomic store.

#define SEQ_LEN 4096
#define HID 1024
#define NBLK 128
#define TPB 512
#define HPB 8      // h-indices per block (one per wave)

__device__ __forceinline__ float fast_sigmoid(float x) {
    return __builtin_amdgcn_rcpf(1.0f + __builtin_amdgcn_exp2f(-1.4426950408889634f * x));
}
__device__ __forceinline__ float fast_tanh(float x) {
    return fmaf(-2.0f, __builtin_amdgcn_rcpf(1.0f + __builtin_amdgcn_exp2f(2.8853900817779268f * x)), 1.0f);
}

// ws: unsigned long long slots[2][1024]. {tag<<32 | fp32 bits}. Zero-init:
// buffer0 tag0/val0 == h_0 = 0 (correct); buffer1 receives odd tags.
__global__ void lstm_init_kernel(unsigned long long* ws) {
    int t = threadIdx.x;
    #pragma unroll
    for (int k = 0; k < 8; ++k) ws[t + 256 * k] = 0ull;
}

__global__ __launch_bounds__(TPB, 1) void lstm_persistent_kernel(
    const float* __restrict__ input,   // [4096][64]
    const float* __restrict__ W_ih,    // [4096][64]
    const float* __restrict__ W_hh,    // [4096][1024]
    const float* __restrict__ b_ih,    // [4096]
    const float* __restrict__ b_hh,    // [4096]
    const float* __restrict__ W_lin,   // [1][1024]
    const float* __restrict__ b_lin,   // [1]
    float* __restrict__ out,           // [1]
    unsigned long long* __restrict__ ws)
{
    const int t   = threadIdx.x;
    const int b   = blockIdx.x;
    const int w   = t >> 6;      // wave in block (0..7)
    const int l   = t & 63;      // lane
    const int grp = l >> 4;      // gate q (i,f,g,o)
    const int sl  = l & 15;      // sub-lane within gate group
    const int j   = HPB * b + w; // owned h index
    const int row = grp * HID + j;

    unsigned long long* slot0 = ws;          // even tags
    unsigned long long* slot1 = ws + HID;    // odd tags

    __shared__ float4 wlds4[17 * TPB];       // 136 KB weight staging
    __shared__ float  hs[2][HID];            // double-buffered h (8 KB)
    __shared__ unsigned long long pub[HPB];  // tagged intra-block handoff
    __shared__ float  red[HPB];

    // ---- stage this block's 32 gate-rows into LDS ----
    {
        const float4* Whh4 = (const float4*)(W_hh + (size_t)row * HID);
        #pragma unroll
        for (int c = 0; c < 16; ++c)
            wlds4[c * TPB + t] = Whh4[sl + 16 * c];     // W_hh[row][64c+4sl..+3]
        wlds4[16 * TPB + t] = ((const float4*)(W_ih + (size_t)row * 64))[sl];
    }
    float bias[4];
    #pragma unroll
    for (int q = 0; q < 4; ++q) bias[q] = b_ih[q * HID + j] + b_hh[q * HID + j];
    if (t < HPB) pub[t] = 0ull;
    __syncthreads();   // weights staged, pub initialized

    // ---- LDS -> named registers (r9) ----
    const float4 W0  = wlds4[ 0 * TPB + t];
    const float4 W1  = wlds4[ 1 * TPB + t];
    const float4 W2  = wlds4[ 2 * TPB + t];
    const float4 W3  = wlds4[ 3 * TPB + t];
    const float4 W4  = wlds4[ 4 * TPB + t];
    const float4 W5  = wlds4[ 5 * TPB + t];
    const float4 W6  = wlds4[ 6 * TPB + t];
    const float4 W7  = wlds4[ 7 * TPB + t];
    const float4 W8  = wlds4[ 8 * TPB + t];
    const float4 W9  = wlds4[ 9 * TPB + t];
    const float4 W10 = wlds4[10 * TPB + t];
    const float4 W11 = wlds4[11 * TPB + t];
    const float4 W12 = wlds4[12 * TPB + t];
    const float4 W13 = wlds4[13 * TPB + t];
    const float4 W14 = wlds4[14 * TPB + t];
    const float4 W15 = wlds4[15 * TPB + t];
    const float4 W16 = wlds4[16 * TPB + t];   // W_ih fragment

    const float4* xin4 = (const float4*)input;
    float c_state = 0.0f;

    for (int s = 0; s < SEQ_LEN; ++s) {
        float4 x4 = xin4[s * 16 + sl];   // issue before poll; value lands in regs

        // ---- poll 2 tagged slots: buffer_inv + cacheable loads (MALL-hit) ----
        unsigned long long* rs = (s & 1) ? slot1 : slot0;
        const unsigned tag = (unsigned)s;
        unsigned long long v0, v1;
        bool r0 = false, r1 = false;
        do {
            asm volatile("buffer_inv sc1" ::: "memory");   // L1+L2 flash-inv -> next loads hit MALL
            if (!r0) { v0 = __hip_atomic_load(&rs[t      ], __ATOMIC_RELAXED, __HIP_MEMORY_SCOPE_WORKGROUP);
                       r0 = ((unsigned)(v0 >> 32) == tag); }
            if (!r1) { v1 = __hip_atomic_load(&rs[t + 512], __ATOMIC_RELAXED, __HIP_MEMORY_SCOPE_WORKGROUP);
                       r1 = ((unsigned)(v1 >> 32) == tag); }
        } while (!(r0 && r1));

        float* hsb = hs[s & 1];
        hsb[t      ] = __uint_as_float((unsigned)(v0 & 0xffffffffull));
        hsb[t + 512] = __uint_as_float((unsigned)(v1 & 0xffffffffull));

        __syncthreads();   // the ONE barrier per step: full h_s staged

        // ---- 68 FMAs: weights from registers, h broadcast-read from LDS ----
        const float4* hs4 = (const float4*)hsb;
        float a0 = 0.f, a1 = 0.f, a2 = 0.f, a3 = 0.f;
        #define FMA_CHUNK(Wc, c, acc) { float4 h4_ = hs4[16 * (c) + sl];      \
            acc = fmaf((Wc).x, h4_.x, acc); acc = fmaf((Wc).y, h4_.y, acc);   \
            acc = fmaf((Wc).z, h4_.z, acc); acc = fmaf((Wc).w, h4_.w, acc); }
        FMA_CHUNK(W0,  0, a0) FMA_CHUNK(W1,  1, a1)
        FMA_CHUNK(W2,  2, a2) FMA_CHUNK(W3,  3, a3)
        FMA_CHUNK(W4,  4, a0) FMA_CHUNK(W5,  5, a1)
        FMA_CHUNK(W6,  6, a2) FMA_CHUNK(W7,  7, a3)
        FMA_CHUNK(W8,  8, a0) FMA_CHUNK(W9,  9, a1)
        FMA_CHUNK(W10, 10, a2) FMA_CHUNK(W11, 11, a3)
        FMA_CHUNK(W12, 12, a0) FMA_CHUNK(W13, 13, a1)
        FMA_CHUNK(W14, 14, a2) FMA_CHUNK(W15, 15, a3)
        #undef FMA_CHUNK
        a0 = fmaf(W16.x, x4.x, a0); a1 = fmaf(W16.y, x4.y, a1);
        a2 = fmaf(W16.z, x4.z, a2); a3 = fmaf(W16.w, x4.w, a3);
        float acc = (a0 + a1) + (a2 + a3);

        // reduce across 16 lanes of the gate group
        acc += __shfl_xor(acc, 1);
        acc += __shfl_xor(acc, 2);
        acc += __shfl_xor(acc, 4);
        acc += __shfl_xor(acc, 8);

        float gi = __shfl(acc, 0)  + bias[0];
        float gf = __shfl(acc, 16) + bias[1];
        float gg = __shfl(acc, 32) + bias[2];
        float go = __shfl(acc, 48) + bias[3];

        float ig = fast_sigmoid(gi);
        float fg = fast_sigmoid(gf);
        float cg = fast_tanh(gg);
        float og = fast_sigmoid(go);
        c_state  = fmaf(fg, c_state, ig * cg);
        float hn = og * fast_tanh(c_state);

        // ---- intra-block handoff: wave w lane 0 posts tagged hn to LDS ----
        const unsigned ntag = (unsigned)(s + 1);
        if (l == 0) {
            unsigned long long pv = ((unsigned long long)ntag << 32) |
                                    (unsigned long long)__float_as_uint(hn);
            __hip_atomic_store(&pub[w], pv, __ATOMIC_RELAXED, __HIP_MEMORY_SCOPE_WORKGROUP);
        }
        // ---- wave 0 lanes 0..7 gather the 8 words, publish one 64B line ----
        if (w == 0 && l < HPB) {
            unsigned long long pv;
            do {
                pv = __hip_atomic_load(&pub[l], __ATOMIC_RELAXED, __HIP_MEMORY_SCOPE_WORKGROUP);
            } while ((unsigned)(pv >> 32) != ntag);
            unsigned long long* wsl = (s & 1) ? slot0 : slot1;   // buffer (s+1)&1
            __hip_atomic_store(&wsl[HPB * b + l], pv, __ATOMIC_RELAXED, __HIP_MEMORY_SCOPE_AGENT);
        }
        // no trailing barrier: hs double-buffered; slot-tag deps bound skew
    }

    // ---- final projection: h_4096 (tag 4096, even -> slot0) . W_lin + b_lin ----
    if (b == 0) {
        const unsigned tag = (unsigned)SEQ_LEN;
        unsigned long long v0, v1;
        bool r0 = false, r1 = false;
        do {
            asm volatile("buffer_inv sc1" ::: "memory");
            if (!r0) { v0 = __hip_atomic_load(&slot0[t      ], __ATOMIC_RELAXED, __HIP_MEMORY_SCOPE_WORKGROUP);
                       r0 = ((unsigned)(v0 >> 32) == tag); }
            if (!r1) { v1 = __hip_atomic_load(&slot0[t + 512], __ATOMIC_RELAXED, __HIP_MEMORY_SCOPE_WORKGROUP);
                       r1 = ((unsigned)(v1 >> 32) == tag); }
        } while (!(r0 && r1));
        float p = __uint_as_float((unsigned)(v0 & 0xffffffffull)) * W_lin[t] +
                  __uint_as_float((unsigned)(v1 & 0xffffffffull)) * W_lin[t + 512];
        #pragma unroll
        for (int m = 32; m >= 1; m >>= 1) p += __shfl_xor(p, m);
        if (l == 0) red[w] = p;
        __syncthreads();
        if (t == 0) {
            float r = 0.f;
            #pragma unroll
            for (int k = 0; k < HPB; ++k) r += red[k];
            out[0] = r + b_lin[0];
        }
    }
}

extern "C" void kernel_launch(void* const* d_in, const int* in_sizes, int n_in,
                              void* d_out, int out_size, void* d_ws, size_t ws_size,
                              hipStream_t stream) {
    const float* input = (const float*)d_in[0];
    const float* W_ih  = (const float*)d_in[1];
    const float* W_hh  = (const float*)d_in[2];
    const float* b_ih  = (const float*)d_in[3];
    const float* b_hh  = (const float*)d_in[4];
    const float* W_lin = (const float*)d_in[5];
    const float* b_lin = (const float*)d_in[6];
    float* out = (float*)d_out;
    unsigned long long* ws = (unsigned long long*)d_ws;

    hipLaunchKernelGGL(lstm_init_kernel, dim3(1), dim3(256), 0, stream, ws);

    void* args[] = { (void*)&input, (void*)&W_ih, (void*)&W_hh, (void*)&b_ih,
                     (void*)&b_hh, (void*)&W_lin, (void*)&b_lin, (void*)&out, (void*)&ws };
    (void)hipLaunchCooperativeKernel((void*)lstm_persistent_kernel, dim3(NBLK), dim3(TPB),
                                     args, 0, stream);
}

// Round 14
// 10072.527 us; speedup vs baseline: 5.6546x; 5.6546x over previous
//
#include <hip/hip_runtime.h>

// LSTM: S=4096, I=64, H=1024, O=1, fp32.
// Persistent cooperative kernel, 128 blocks x 512 threads (r9 champion base).
// R14: pipelined multi-issue polling. r9's poll serializes a full MALL RTT
// (~700-900cy) per iteration; a just-missed flip costs ~1-1.5 iterations.
// Fix: per iteration, issue 4 independent volatile samples of each slot
// back-to-back (8 loads in flight; volatile lowers to sc0+sc1 dwordx2 =
// same bypass/visibility as the agent atomics used since r5), then check
// oldest-first under the compiler's partial vmcnt waits. Sampling period
// drops from ~RTT to ~loop-issue (~150cy): saves ~500-700cy/step.
// r13 lesson: buffer_inv-per-poll is catastrophic (57ms) — never again.
// Everything else r9: tagged slots {tag:32|h_bits:32}, tagged double buffer,
// zero fences, ONE barrier/step, weights in named registers, wave0 gather +
// coalesced 64B line publish (WRITE_SIZE must stay 32768 KB).

#define SEQ_LEN 4096
#define HID 1024
#define NBLK 128
#define TPB 512
#define HPB 8      // h-indices per block (one per wave)

__device__ __forceinline__ float fast_sigmoid(float x) {
    return __builtin_amdgcn_rcpf(1.0f + __builtin_amdgcn_exp2f(-1.4426950408889634f * x));
}
__device__ __forceinline__ float fast_tanh(float x) {
    return fmaf(-2.0f, __builtin_amdgcn_rcpf(1.0f + __builtin_amdgcn_exp2f(2.8853900817779268f * x)), 1.0f);
}

// ws: unsigned long long slots[2][1024]. {tag<<32 | fp32 bits}. Zero-init:
// buffer0 tag0/val0 == h_0 = 0 (correct); buffer1 receives odd tags.
__global__ void lstm_init_kernel(unsigned long long* ws) {
    int t = threadIdx.x;
    #pragma unroll
    for (int k = 0; k < 8; ++k) ws[t + 256 * k] = 0ull;
}

__global__ __launch_bounds__(TPB, 1) void lstm_persistent_kernel(
    const float* __restrict__ input,   // [4096][64]
    const float* __restrict__ W_ih,    // [4096][64]
    const float* __restrict__ W_hh,    // [4096][1024]
    const float* __restrict__ b_ih,    // [4096]
    const float* __restrict__ b_hh,    // [4096]
    const float* __restrict__ W_lin,   // [1][1024]
    const float* __restrict__ b_lin,   // [1]
    float* __restrict__ out,           // [1]
    unsigned long long* __restrict__ ws)
{
    const int t   = threadIdx.x;
    const int b   = blockIdx.x;
    const int w   = t >> 6;      // wave in block (0..7)
    const int l   = t & 63;      // lane
    const int grp = l >> 4;      // gate q (i,f,g,o)
    const int sl  = l & 15;      // sub-lane within gate group
    const int j   = HPB * b + w; // owned h index
    const int row = grp * HID + j;

    unsigned long long* slot0 = ws;          // even tags
    unsigned long long* slot1 = ws + HID;    // odd tags

    __shared__ float4 wlds4[17 * TPB];       // 136 KB weight staging
    __shared__ float  hs[2][HID];            // double-buffered h (8 KB)
    __shared__ unsigned long long pub[HPB];  // tagged intra-block handoff
    __shared__ float  red[HPB];

    // ---- stage this block's 32 gate-rows into LDS ----
    {
        const float4* Whh4 = (const float4*)(W_hh + (size_t)row * HID);
        #pragma unroll
        for (int c = 0; c < 16; ++c)
            wlds4[c * TPB + t] = Whh4[sl + 16 * c];     // W_hh[row][64c+4sl..+3]
        wlds4[16 * TPB + t] = ((const float4*)(W_ih + (size_t)row * 64))[sl];
    }
    float bias[4];
    #pragma unroll
    for (int q = 0; q < 4; ++q) bias[q] = b_ih[q * HID + j] + b_hh[q * HID + j];
    if (t < HPB) pub[t] = 0ull;
    __syncthreads();   // weights staged, pub initialized

    // ---- LDS -> named registers (r9) ----
    const float4 W0  = wlds4[ 0 * TPB + t];
    const float4 W1  = wlds4[ 1 * TPB + t];
    const float4 W2  = wlds4[ 2 * TPB + t];
    const float4 W3  = wlds4[ 3 * TPB + t];
    const float4 W4  = wlds4[ 4 * TPB + t];
    const float4 W5  = wlds4[ 5 * TPB + t];
    const float4 W6  = wlds4[ 6 * TPB + t];
    const float4 W7  = wlds4[ 7 * TPB + t];
    const float4 W8  = wlds4[ 8 * TPB + t];
    const float4 W9  = wlds4[ 9 * TPB + t];
    const float4 W10 = wlds4[10 * TPB + t];
    const float4 W11 = wlds4[11 * TPB + t];
    const float4 W12 = wlds4[12 * TPB + t];
    const float4 W13 = wlds4[13 * TPB + t];
    const float4 W14 = wlds4[14 * TPB + t];
    const float4 W15 = wlds4[15 * TPB + t];
    const float4 W16 = wlds4[16 * TPB + t];   // W_ih fragment

    const float4* xin4 = (const float4*)input;
    float c_state = 0.0f;

    for (int s = 0; s < SEQ_LEN; ++s) {
        float4 x4 = xin4[s * 16 + sl];   // issue before poll (cacheable)

        // ---- pipelined poll: 4 in-flight samples per slot per iteration ----
        volatile const unsigned long long* rsv = (s & 1) ? slot1 : slot0;
        const unsigned tag = (unsigned)s;
        unsigned long long v0, v1;
        bool r0 = false, r1 = false;
        do {
            unsigned long long s00 = rsv[t];       unsigned long long s10 = rsv[t + 512];
            unsigned long long s01 = rsv[t];       unsigned long long s11 = rsv[t + 512];
            unsigned long long s02 = rsv[t];       unsigned long long s12 = rsv[t + 512];
            unsigned long long s03 = rsv[t];       unsigned long long s13 = rsv[t + 512];
            if (!r0) {
                if      ((unsigned)(s00 >> 32) == tag) { v0 = s00; r0 = true; }
                else if ((unsigned)(s01 >> 32) == tag) { v0 = s01; r0 = true; }
                else if ((unsigned)(s02 >> 32) == tag) { v0 = s02; r0 = true; }
                else if ((unsigned)(s03 >> 32) == tag) { v0 = s03; r0 = true; }
            }
            if (!r1) {
                if      ((unsigned)(s10 >> 32) == tag) { v1 = s10; r1 = true; }
                else if ((unsigned)(s11 >> 32) == tag) { v1 = s11; r1 = true; }
                else if ((unsigned)(s12 >> 32) == tag) { v1 = s12; r1 = true; }
                else if ((unsigned)(s13 >> 32) == tag) { v1 = s13; r1 = true; }
            }
        } while (!(r0 && r1));

        float* hsb = hs[s & 1];
        hsb[t      ] = __uint_as_float((unsigned)(v0 & 0xffffffffull));
        hsb[t + 512] = __uint_as_float((unsigned)(v1 & 0xffffffffull));

        __syncthreads();   // the ONE barrier per step: full h_s staged

        // ---- 68 FMAs: weights from registers, h broadcast-read from LDS ----
        const float4* hs4 = (const float4*)hsb;
        float a0 = 0.f, a1 = 0.f, a2 = 0.f, a3 = 0.f;
        #define FMA_CHUNK(Wc, c, acc) { float4 h4_ = hs4[16 * (c) + sl];      \
            acc = fmaf((Wc).x, h4_.x, acc); acc = fmaf((Wc).y, h4_.y, acc);   \
            acc = fmaf((Wc).z, h4_.z, acc); acc = fmaf((Wc).w, h4_.w, acc); }
        FMA_CHUNK(W0,  0, a0) FMA_CHUNK(W1,  1, a1)
        FMA_CHUNK(W2,  2, a2) FMA_CHUNK(W3,  3, a3)
        FMA_CHUNK(W4,  4, a0) FMA_CHUNK(W5,  5, a1)
        FMA_CHUNK(W6,  6, a2) FMA_CHUNK(W7,  7, a3)
        FMA_CHUNK(W8,  8, a0) FMA_CHUNK(W9,  9, a1)
        FMA_CHUNK(W10, 10, a2) FMA_CHUNK(W11, 11, a3)
        FMA_CHUNK(W12, 12, a0) FMA_CHUNK(W13, 13, a1)
        FMA_CHUNK(W14, 14, a2) FMA_CHUNK(W15, 15, a3)
        #undef FMA_CHUNK
        a0 = fmaf(W16.x, x4.x, a0); a1 = fmaf(W16.y, x4.y, a1);
        a2 = fmaf(W16.z, x4.z, a2); a3 = fmaf(W16.w, x4.w, a3);
        float acc = (a0 + a1) + (a2 + a3);

        // reduce across 16 lanes of the gate group
        acc += __shfl_xor(acc, 1);
        acc += __shfl_xor(acc, 2);
        acc += __shfl_xor(acc, 4);
        acc += __shfl_xor(acc, 8);

        float gi = __shfl(acc, 0)  + bias[0];
        float gf = __shfl(acc, 16) + bias[1];
        float gg = __shfl(acc, 32) + bias[2];
        float go = __shfl(acc, 48) + bias[3];

        float ig = fast_sigmoid(gi);
        float fg = fast_sigmoid(gf);
        float cg = fast_tanh(gg);
        float og = fast_sigmoid(go);
        c_state  = fmaf(fg, c_state, ig * cg);
        float hn = og * fast_tanh(c_state);

        // ---- intra-block handoff: wave w lane 0 posts tagged hn to LDS ----
        const unsigned ntag = (unsigned)(s + 1);
        if (l == 0) {
            unsigned long long pv = ((unsigned long long)ntag << 32) |
                                    (unsigned long long)__float_as_uint(hn);
            __hip_atomic_store(&pub[w], pv, __ATOMIC_RELAXED, __HIP_MEMORY_SCOPE_WORKGROUP);
        }
        // ---- wave 0 lanes 0..7 gather the 8 words, publish one 64B line ----
        if (w == 0 && l < HPB) {
            unsigned long long pv;
            do {
                pv = __hip_atomic_load(&pub[l], __ATOMIC_RELAXED, __HIP_MEMORY_SCOPE_WORKGROUP);
            } while ((unsigned)(pv >> 32) != ntag);
            unsigned long long* wsl = (s & 1) ? slot0 : slot1;   // buffer (s+1)&1
            __hip_atomic_store(&wsl[HPB * b + l], pv, __ATOMIC_RELAXED, __HIP_MEMORY_SCOPE_AGENT);
        }
        // no trailing barrier: hs double-buffered; slot-tag deps bound skew
    }

    // ---- final projection: h_4096 (tag 4096, even -> slot0) . W_lin + b_lin ----
    if (b == 0) {
        volatile const unsigned long long* rsv = slot0;
        const unsigned tag = (unsigned)SEQ_LEN;
        unsigned long long v0, v1;
        bool r0 = false, r1 = false;
        do {
            unsigned long long s00 = rsv[t];       unsigned long long s10 = rsv[t + 512];
            unsigned long long s01 = rsv[t];       unsigned long long s11 = rsv[t + 512];
            if (!r0) {
                if      ((unsigned)(s00 >> 32) == tag) { v0 = s00; r0 = true; }
                else if ((unsigned)(s01 >> 32) == tag) { v0 = s01; r0 = true; }
            }
            if (!r1) {
                if      ((unsigned)(s10 >> 32) == tag) { v1 = s10; r1 = true; }
                else if ((unsigned)(s11 >> 32) == tag) { v1 = s11; r1 = true; }
            }
        } while (!(r0 && r1));
        float p = __uint_as_float((unsigned)(v0 & 0xffffffffull)) * W_lin[t] +
                  __uint_as_float((unsigned)(v1 & 0xffffffffull)) * W_lin[t + 512];
        #pragma unroll
        for (int m = 32; m >= 1; m >>= 1) p += __shfl_xor(p, m);
        if (l == 0) red[w] = p;
        __syncthreads();
        if (t == 0) {
            float r = 0.f;
            #pragma unroll
            for (int k = 0; k < HPB; ++k) r += red[k];
            out[0] = r + b_lin[0];
        }
    }
}

extern "C" void kernel_launch(void* const* d_in, const int* in_sizes, int n_in,
                              void* d_out, int out_size, void* d_ws, size_t ws_size,
                              hipStream_t stream) {
    const float* input = (const float*)d_in[0];
    const float* W_ih  = (const float*)d_in[1];
    const float* W_hh  = (const float*)d_in[2];
    const float* b_ih  = (const float*)d_in[3];
    const float* b_hh  = (const float*)d_in[4];
    const float* W_lin = (const float*)d_in[5];
    const float* b_lin = (const float*)d_in[6];
    float* out = (float*)d_out;
    unsigned long long* ws = (unsigned long long*)d_ws;

    hipLaunchKernelGGL(lstm_init_kernel, dim3(1), dim3(256), 0, stream, ws);

    void* args[] = { (void*)&input, (void*)&W_ih, (void*)&W_hh, (void*)&b_ih,
                     (void*)&b_hh, (void*)&W_lin, (void*)&b_lin, (void*)&out, (void*)&ws };
    (void)hipLaunchCooperativeKernel((void*)lstm_persistent_kernel, dim3(NBLK), dim3(TPB),
                                     args, 0, stream);
}